// Round 3
// baseline (1846.656 us; speedup 1.0000x reference)
//
#include <hip/hip_runtime.h>

typedef unsigned short u16;
typedef __bf16 bf16x8 __attribute__((ext_vector_type(8)));
typedef float f32x4 __attribute__((ext_vector_type(4)));

#define NEXP 30
#define INSZ 1024
#define HID 2048
#define NB 8192

// ---------- helpers ----------
__device__ __forceinline__ u16 f2bf(float f) {
    union { float f; unsigned u; } x; x.f = f;
    unsigned r = x.u + 0x7FFFu + ((x.u >> 16) & 1u);   // RNE
    return (u16)(r >> 16);
}

typedef __attribute__((address_space(3))) unsigned int lds_u32;
typedef const __attribute__((address_space(1))) unsigned int glb_u32;
__device__ __forceinline__ void gl2lds16(const void* g, void* l) {
    // async global->LDS, 16B per lane; LDS dest must be wave-uniform base + lane*16
    __builtin_amdgcn_global_load_lds((glb_u32*)g, (lds_u32*)l, 16, 0, 0);
}

struct alignas(16) U16x8 { u16 v[8]; };

// ---------- conversion: x fp32 -> bf16 (same layout) ----------
__global__ __launch_bounds__(256) void conv_x(const float* __restrict__ in,
                                              u16* __restrict__ out) {
    size_t base = ((size_t)blockIdx.x * 256 + threadIdx.x) * 8;
    float4 v0 = *(const float4*)(in + base);
    float4 v1 = *(const float4*)(in + base + 4);
    U16x8 o;
    o.v[0] = f2bf(v0.x); o.v[1] = f2bf(v0.y); o.v[2] = f2bf(v0.z); o.v[3] = f2bf(v0.w);
    o.v[4] = f2bf(v1.x); o.v[5] = f2bf(v1.y); o.v[6] = f2bf(v1.z); o.v[7] = f2bf(v1.w);
    *(U16x8*)(out + base) = o;
}

// ---------- conversion: W1 [E][I][H] fp32 -> Wt [E][H][I] bf16 ----------
// tile i=32 x h=256; coalesced float4 reads; each thread owns one h row and
// writes 64 contiguous bytes (4 x dwordx4). LDS [32][260] fp32: 16B-aligned
// rows (260*4 % 16 == 0), bank-shift 4/row, 2-way max on reads.
__global__ __launch_bounds__(256) void conv_w1(const float* __restrict__ W1,
                                               u16* __restrict__ Wt) {
    __shared__ float t[32][260];
    const int e  = blockIdx.z;
    const int i0 = blockIdx.x * 32;
    const int h0 = blockIdx.y * 256;
    const int tid = threadIdx.x;
    const float* src = W1 + (size_t)e * INSZ * HID;
    u16* dst = Wt + (size_t)e * HID * INSZ;

    const int rr = tid >> 6;          // 0..3
    const int c4 = (tid & 63) * 4;    // float4 col
    #pragma unroll
    for (int p = 0; p < 8; p++) {
        const int row = p * 4 + rr;
        float4 v = *(const float4*)&src[(size_t)(i0 + row) * HID + h0 + c4];
        *(float4*)&t[row][c4] = v;
    }
    __syncthreads();

    const int h = tid;                // 0..255
    U16x8 o[4];
    #pragma unroll
    for (int g = 0; g < 4; g++)
        #pragma unroll
        for (int j = 0; j < 8; j++)
            o[g].v[j] = f2bf(t[g * 8 + j][h]);
    u16* d = dst + (size_t)(h0 + h) * INSZ + i0;
    #pragma unroll
    for (int g = 0; g < 4; g++)
        *(U16x8*)(d + g * 8) = o[g];
}

// ---------- fused fc1(MFMA bf16) + ReLU + fc2 + sigmoid + mean ----------
// 256x256 tile, BK=32, 8 waves (2M x 4N), 4-slot LDS ring, vmcnt(8) window,
// ONE barrier per K-step; all frag reads + stages issued at region start so
// the compiler interleaves ds_read drain under the 32-MFMA cluster.
__global__ __launch_bounds__(512, 2) void fused_mlp(
        const u16* __restrict__ Xb,   // [NB][INSZ] bf16
        const u16* __restrict__ Wt,   // [E][HID][INSZ] bf16
        const float* __restrict__ b1, // [E][HID]
        const float* __restrict__ W2, // [E][HID]
        const float* __restrict__ b2, // [E]
        float* __restrict__ out)      // [NB]
{
    // ring[slot][A=0/B=1][ [half2][q4][row128][8] u16 ] = 128 KiB
    __shared__ __attribute__((aligned(16))) u16 ring[4][2][8192];
    __shared__ float rsum[256];

    const int e     = blockIdx.y;
    const int mbase = blockIdx.x * 256;
    const int tid   = threadIdx.x;      // 0..511
    const int lane  = tid & 63;
    const int wid   = tid >> 6;         // 0..7
    const int q     = lane >> 4;        // k-quad
    const int c     = lane & 15;        // row/col within frag
    const int wr    = wid >> 2;         // 0..1 : 128-row half
    const int wc    = wid & 3;          // 0..3 : 64-col quarter

    // staging source map: LDS linear dest tid*16B == [q=tid>>7][row=tid&127][8]
    const int srow = tid & 127;
    const int sq8  = (tid >> 7) * 8;
    const u16* xsrc = Xb + (size_t)(mbase + srow) * INSZ + sq8;
    const u16* wsrc = Wt + (size_t)e * HID * INSZ + (size_t)srow * INSZ + sq8;
    const float* b1e = b1 + e * HID;
    const float* w2e = W2 + e * HID;

    // fragment read bases (u16 units): [half][q][row][8]
    const int a_base = wr * 4096 + q * 1024 + c * 8;
    const int b_base = (wc >> 1) * 4096 + q * 1024 + (wc & 1) * 512 + c * 8;

    f32x4 acc[8][4];
    #pragma unroll
    for (int mi = 0; mi < 8; mi++)
        #pragma unroll
        for (int ni = 0; ni < 4; ni++)
            acc[mi][ni] = f32x4{0.f, 0.f, 0.f, 0.f};

    if (tid < 256) rsum[tid] = 0.f;

    // prologue: stage tiles 0,1,2 into slots 0,1,2
    #pragma unroll
    for (int tpre = 0; tpre < 3; ++tpre) {
        const int k0 = tpre * 32;
        gl2lds16(xsrc + k0,                       &ring[tpre][0][tid * 8]);
        gl2lds16(xsrc + k0 + (size_t)128 * INSZ,  &ring[tpre][0][4096 + tid * 8]);
        gl2lds16(wsrc + k0,                       &ring[tpre][1][tid * 8]);
        gl2lds16(wsrc + k0 + (size_t)128 * INSZ,  &ring[tpre][1][4096 + tid * 8]);
    }

#define KT_ITER(U)                                                             \
    {                                                                          \
        const int t  = nt * 32 + kt4 + (U);                                    \
        int tc = t + 3; if (tc > 255) tc = 255;                                \
        const int k3 = (tc & 31) * 32;                                         \
        const int n3 = (tc >> 5) * 256;                                        \
        const int slot = (U) & 3;                                              \
        const int s3   = ((U) + 3) & 3;                                        \
        /* boundary: allow only t+1/t+2 stages (8 newest) in flight */         \
        asm volatile("s_waitcnt vmcnt(8)" ::: "memory");                       \
        __builtin_amdgcn_s_barrier();                                          \
        __builtin_amdgcn_sched_barrier(0);                                     \
        /* stage tile t+3 (A then B) */                                        \
        gl2lds16(xsrc + k3,                      &ring[s3][0][tid * 8]);       \
        gl2lds16(xsrc + k3 + (size_t)128 * INSZ, &ring[s3][0][4096 + tid * 8]);\
        {                                                                      \
            const u16* ws = wsrc + (size_t)n3 * INSZ + k3;                     \
            gl2lds16(ws,                      &ring[s3][1][tid * 8]);          \
            gl2lds16(ws + (size_t)128 * INSZ, &ring[s3][1][4096 + tid * 8]);   \
        }                                                                      \
        /* all 12 fragment reads; compiler interleaves drain under MFMAs */    \
        bf16x8 af[4], bv[4], af2[4];                                           \
        _Pragma("unroll")                                                      \
        for (int ni = 0; ni < 4; ni++)                                         \
            bv[ni] = *(const bf16x8*)&ring[slot][1][b_base + ni * 128];        \
        _Pragma("unroll")                                                      \
        for (int mi = 0; mi < 4; mi++)                                         \
            af[mi] = *(const bf16x8*)&ring[slot][0][a_base + mi * 128];        \
        _Pragma("unroll")                                                      \
        for (int mi = 0; mi < 4; mi++)                                         \
            af2[mi] = *(const bf16x8*)&ring[slot][0][a_base + (4 + mi) * 128]; \
        __builtin_amdgcn_s_setprio(1);                                         \
        _Pragma("unroll")                                                      \
        for (int mi = 0; mi < 4; mi++)                                         \
            _Pragma("unroll")                                                  \
            for (int ni = 0; ni < 4; ni++)                                     \
                acc[mi][ni] = __builtin_amdgcn_mfma_f32_16x16x32_bf16(         \
                    af[mi], bv[ni], acc[mi][ni], 0, 0, 0);                     \
        _Pragma("unroll")                                                      \
        for (int mi = 0; mi < 4; mi++)                                         \
            _Pragma("unroll")                                                  \
            for (int ni = 0; ni < 4; ni++)                                     \
                acc[4 + mi][ni] = __builtin_amdgcn_mfma_f32_16x16x32_bf16(     \
                    af2[mi], bv[ni], acc[4 + mi][ni], 0, 0, 0);                \
        __builtin_amdgcn_s_setprio(0);                                         \
    }

    #pragma unroll 1
    for (int nt = 0; nt < 8; ++nt) {
        // hoist epilogue operands; force-drained harmlessly at first boundary
        float bb[4], ww[4];
        #pragma unroll
        for (int ni = 0; ni < 4; ni++) {
            const int n = nt * 256 + wc * 64 + ni * 16 + c;
            bb[ni] = b1e[n];
            ww[ni] = w2e[n];
        }
        #pragma unroll 1
        for (int kt4 = 0; kt4 < 32; kt4 += 4) {
            KT_ITER(0)
            KT_ITER(1)
            KT_ITER(2)
            KT_ITER(3)
        }
        // epilogue: +b1, ReLU, *W2, reduce across the 16 c-lanes, LDS-accumulate
        #pragma unroll
        for (int mi = 0; mi < 8; mi++)
            #pragma unroll
            for (int r = 0; r < 4; r++) {
                float v = 0.f;
                #pragma unroll
                for (int ni = 0; ni < 4; ni++) {
                    float h = fmaxf(acc[mi][ni][r] + bb[ni], 0.f);
                    v = fmaf(h, ww[ni], v);
                    acc[mi][ni][r] = 0.f;
                }
                v += __shfl_xor(v, 1); v += __shfl_xor(v, 2);
                v += __shfl_xor(v, 4); v += __shfl_xor(v, 8);
                if (c == 0) atomicAdd(&rsum[wr * 128 + mi * 16 + q * 4 + r], v);
            }
    }
#undef KT_ITER

    // drain dead tail stages, then final reduce + sigmoid + mean
    asm volatile("s_waitcnt vmcnt(0)" ::: "memory");
    __syncthreads();
    if (tid < 256) {
        float z = rsum[tid] + b2[e];
        float s = 1.f / (1.f + __expf(-z));
        atomicAdd(&out[mbase + tid], s * (1.0f / NEXP));
    }
}

// ---------- slow-but-correct fallback (only if ws too small) ----------
__global__ __launch_bounds__(256) void fallback_kernel(
        const float* __restrict__ x, const float* __restrict__ W1,
        const float* __restrict__ b1, const float* __restrict__ W2,
        const float* __restrict__ b2, float* __restrict__ out)
{
    __shared__ float xs[64 * 128];   // 32 KB
    __shared__ float zsum[64];
    const int e  = blockIdx.y;
    const int r0 = blockIdx.x * 64;
    const int tid = threadIdx.x;
    if (tid < 64) zsum[tid] = 0.f;
    const float* W1e = W1 + (size_t)e * INSZ * HID;

    for (int hg = 0; hg < 8; hg++) {
        const int h = hg * 256 + tid;
        float acc[64];
        #pragma unroll
        for (int r = 0; r < 64; r++) acc[r] = 0.f;
        for (int ic = 0; ic < 8; ic++) {
            __syncthreads();
            for (int t = tid; t < 64 * 128; t += 256) {
                int r = t >> 7, i = t & 127;
                xs[t] = x[(size_t)(r0 + r) * INSZ + ic * 128 + i];
            }
            __syncthreads();
            for (int i = 0; i < 128; i++) {
                float wv = W1e[(size_t)(ic * 128 + i) * HID + h];
                #pragma unroll
                for (int r = 0; r < 64; r++)
                    acc[r] = fmaf(xs[r * 128 + i], wv, acc[r]);
            }
        }
        const float bb = b1[e * HID + h];
        const float ww = W2[e * HID + h];
        #pragma unroll
        for (int r = 0; r < 64; r++) {
            float v = fmaxf(acc[r] + bb, 0.f) * ww;
            v += __shfl_xor(v, 1);  v += __shfl_xor(v, 2);  v += __shfl_xor(v, 4);
            v += __shfl_xor(v, 8);  v += __shfl_xor(v, 16); v += __shfl_xor(v, 32);
            if ((tid & 63) == 0) atomicAdd(&zsum[r], v);
        }
    }
    __syncthreads();
    if (tid < 64) {
        float z = zsum[tid] + b2[e];
        atomicAdd(&out[r0 + tid], (1.f / (1.f + __expf(-z))) * (1.0f / NEXP));
    }
}

extern "C" void kernel_launch(void* const* d_in, const int* in_sizes, int n_in,
                              void* d_out, int out_size, void* d_ws, size_t ws_size,
                              hipStream_t stream) {
    const float* x  = (const float*)d_in[0];
    const float* W1 = (const float*)d_in[1];
    const float* b1 = (const float*)d_in[2];
    const float* W2 = (const float*)d_in[3];
    const float* b2 = (const float*)d_in[4];
    float* out = (float*)d_out;

    hipMemsetAsync(out, 0, (size_t)out_size * sizeof(float), stream);

    const size_t xb_bytes = (size_t)NB * INSZ * sizeof(u16);          // 16 MB
    const size_t wt_bytes = (size_t)NEXP * HID * INSZ * sizeof(u16);  // 126 MB
    if (ws_size >= xb_bytes + wt_bytes) {
        u16* Xb = (u16*)d_ws;
        u16* Wt = (u16*)((char*)d_ws + xb_bytes);
        conv_x<<<dim3((NB * INSZ) / 2048), 256, 0, stream>>>(x, Xb);
        conv_w1<<<dim3(INSZ / 32, HID / 256, NEXP), 256, 0, stream>>>(W1, Wt);
        fused_mlp<<<dim3(NB / 256, NEXP), 512, 0, stream>>>(Xb, Wt, b1, W2, b2, out);
    } else {
        fallback_kernel<<<dim3(NB / 64, NEXP), 256, 0, stream>>>(x, W1, b1, W2, b2, out);
    }
}

// Round 5
// 1783.383 us; speedup vs baseline: 1.0355x; 1.0355x over previous
//
#include <hip/hip_runtime.h>

typedef unsigned short u16;
typedef __bf16 bf16x8 __attribute__((ext_vector_type(8)));
typedef float f32x4 __attribute__((ext_vector_type(4)));

#define NEXP 30
#define INSZ 1024
#define HID 2048
#define NB 8192

// ---------- helpers ----------
__device__ __forceinline__ u16 f2bf(float f) {
    union { float f; unsigned u; } x; x.f = f;
    unsigned r = x.u + 0x7FFFu + ((x.u >> 16) & 1u);   // RNE
    return (u16)(r >> 16);
}

typedef __attribute__((address_space(3))) unsigned int lds_u32;
typedef const __attribute__((address_space(1))) unsigned int glb_u32;
__device__ __forceinline__ void gl2lds16(const void* g, void* l) {
    // async global->LDS, 16B per lane; LDS dest must be wave-uniform base + lane*16
    __builtin_amdgcn_global_load_lds((glb_u32*)g, (lds_u32*)l, 16, 0, 0);
}

struct alignas(16) U16x8 { u16 v[8]; };

// ---------- conversion: x fp32 -> bf16 (same layout) ----------
__global__ __launch_bounds__(256) void conv_x(const float* __restrict__ in,
                                              u16* __restrict__ out) {
    size_t base = ((size_t)blockIdx.x * 256 + threadIdx.x) * 8;
    float4 v0 = *(const float4*)(in + base);
    float4 v1 = *(const float4*)(in + base + 4);
    U16x8 o;
    o.v[0] = f2bf(v0.x); o.v[1] = f2bf(v0.y); o.v[2] = f2bf(v0.z); o.v[3] = f2bf(v0.w);
    o.v[4] = f2bf(v1.x); o.v[5] = f2bf(v1.y); o.v[6] = f2bf(v1.z); o.v[7] = f2bf(v1.w);
    *(U16x8*)(out + base) = o;
}

// ---------- conversion: W1 [E][I][H] fp32 -> Wt [E][H][I] bf16 ----------
__global__ __launch_bounds__(256) void conv_w1(const float* __restrict__ W1,
                                               u16* __restrict__ Wt) {
    __shared__ float t[32][260];
    const int e  = blockIdx.z;
    const int i0 = blockIdx.x * 32;
    const int h0 = blockIdx.y * 256;
    const int tid = threadIdx.x;
    const float* src = W1 + (size_t)e * INSZ * HID;
    u16* dst = Wt + (size_t)e * HID * INSZ;

    const int rr = tid >> 6;          // 0..3
    const int c4 = (tid & 63) * 4;    // float4 col
    #pragma unroll
    for (int p = 0; p < 8; p++) {
        const int row = p * 4 + rr;
        float4 v = *(const float4*)&src[(size_t)(i0 + row) * HID + h0 + c4];
        *(float4*)&t[row][c4] = v;
    }
    __syncthreads();

    const int h = tid;                // 0..255
    U16x8 o[4];
    #pragma unroll
    for (int g = 0; g < 4; g++)
        #pragma unroll
        for (int j = 0; j < 8; j++)
            o[g].v[j] = f2bf(t[g * 8 + j][h]);
    u16* d = dst + (size_t)(h0 + h) * INSZ + i0;
    #pragma unroll
    for (int g = 0; g < 4; g++)
        *(U16x8*)(d + g * 8) = o[g];
}

// ---------- fused fc1(MFMA bf16) + ReLU + fc2 + sigmoid + mean ----------
// 256x256 tile, BK=32, 8 waves (2M x 4N), 4-slot LDS ring, vmcnt(8) window,
// ONE barrier per K-step. Order within kt is pinned with sched_barrier(0):
//   [12 ds_reads] -> [4 gl2lds stages] -> [32 MFMAs]
// Reads BEFORE stages: gl2lds is an LDS store the alias analysis can't
// disambiguate from the ds_reads; stages-first forces the compiler to emit a
// vmcnt wait before the reads (the R3 regression). Reads-first avoids it.
__global__ __launch_bounds__(512, 2) void fused_mlp(
        const u16* __restrict__ Xb,   // [NB][INSZ] bf16
        const u16* __restrict__ Wt,   // [E][HID][INSZ] bf16
        const float* __restrict__ b1, // [E][HID]
        const float* __restrict__ W2, // [E][HID]
        const float* __restrict__ b2, // [E]
        float* __restrict__ out)      // [NB]
{
    // ring[slot][A=0/B=1][ [half2][q4][row128][8] u16 ] = 128 KiB
    __shared__ __attribute__((aligned(16))) u16 ring[4][2][8192];
    __shared__ float rsum[256];

    const int e     = blockIdx.y;
    const int mbase = blockIdx.x * 256;
    const int tid   = threadIdx.x;      // 0..511
    const int lane  = tid & 63;
    const int wid   = tid >> 6;         // 0..7
    const int q     = lane >> 4;        // k-quad
    const int c     = lane & 15;        // row/col within frag
    const int wr    = wid >> 2;         // 0..1 : 128-row half
    const int wc    = wid & 3;          // 0..3 : 64-col quarter

    // staging source map: LDS linear dest tid*16B == [q=tid>>7][row=tid&127][8]
    const int srow = tid & 127;
    const int sq8  = (tid >> 7) * 8;
    const u16* xsrc = Xb + (size_t)(mbase + srow) * INSZ + sq8;
    const u16* wsrc = Wt + (size_t)e * HID * INSZ + (size_t)srow * INSZ + sq8;
    const float* b1e = b1 + e * HID;
    const float* w2e = W2 + e * HID;

    // fragment read bases (u16 units): [half][q][row][8]
    const int a_base = wr * 4096 + q * 1024 + c * 8;
    const int b_base = (wc >> 1) * 4096 + q * 1024 + (wc & 1) * 512 + c * 8;

    f32x4 acc[8][4];
    #pragma unroll
    for (int mi = 0; mi < 8; mi++)
        #pragma unroll
        for (int ni = 0; ni < 4; ni++)
            acc[mi][ni] = f32x4{0.f, 0.f, 0.f, 0.f};

    if (tid < 256) rsum[tid] = 0.f;

    // prologue: stage tiles 0,1,2 into slots 0,1,2
    #pragma unroll
    for (int tpre = 0; tpre < 3; ++tpre) {
        const int k0 = tpre * 32;
        gl2lds16(xsrc + k0,                       &ring[tpre][0][tid * 8]);
        gl2lds16(xsrc + k0 + (size_t)128 * INSZ,  &ring[tpre][0][4096 + tid * 8]);
        gl2lds16(wsrc + k0,                       &ring[tpre][1][tid * 8]);
        gl2lds16(wsrc + k0 + (size_t)128 * INSZ,  &ring[tpre][1][4096 + tid * 8]);
    }

#define KT_ITER(U)                                                             \
    {                                                                          \
        const int t  = nt * 32 + kt4 + (U);                                    \
        int tc = t + 3; if (tc > 255) tc = 255;                                \
        const int k3 = (tc & 31) * 32;                                         \
        const int n3 = (tc >> 5) * 256;                                        \
        const int slot = (U) & 3;                                              \
        const int s3   = ((U) + 3) & 3;                                        \
        /* boundary: tile t landed (8 newer stage-loads may stay in flight);  */\
        /* lgkmcnt(0): my reads of slot s3 are done before anyone re-stages it */\
        asm volatile("s_waitcnt vmcnt(8) lgkmcnt(0)" ::: "memory");            \
        __builtin_amdgcn_s_barrier();                                          \
        __builtin_amdgcn_sched_barrier(0);                                     \
        /* all 12 fragment reads FIRST (no preceding LDS-store to alias) */    \
        bf16x8 af[4], bv[4], af2[4];                                           \
        _Pragma("unroll")                                                      \
        for (int ni = 0; ni < 4; ni++)                                         \
            bv[ni] = *(const bf16x8*)&ring[slot][1][b_base + ni * 128];        \
        _Pragma("unroll")                                                      \
        for (int mi = 0; mi < 4; mi++)                                         \
            af[mi] = *(const bf16x8*)&ring[slot][0][a_base + mi * 128];        \
        _Pragma("unroll")                                                      \
        for (int mi = 0; mi < 4; mi++)                                         \
            af2[mi] = *(const bf16x8*)&ring[slot][0][a_base + (4 + mi) * 128]; \
        __builtin_amdgcn_sched_barrier(0);                                     \
        /* stage tile t+3 (slot s3) AFTER the reads */                         \
        gl2lds16(xsrc + k3,                      &ring[s3][0][tid * 8]);       \
        gl2lds16(xsrc + k3 + (size_t)128 * INSZ, &ring[s3][0][4096 + tid * 8]);\
        {                                                                      \
            const u16* ws = wsrc + (size_t)n3 * INSZ + k3;                     \
            gl2lds16(ws,                      &ring[s3][1][tid * 8]);          \
            gl2lds16(ws + (size_t)128 * INSZ, &ring[s3][1][4096 + tid * 8]);   \
        }                                                                      \
        __builtin_amdgcn_sched_barrier(0);                                     \
        __builtin_amdgcn_s_setprio(1);                                         \
        _Pragma("unroll")                                                      \
        for (int mi = 0; mi < 4; mi++)                                         \
            _Pragma("unroll")                                                  \
            for (int ni = 0; ni < 4; ni++)                                     \
                acc[mi][ni] = __builtin_amdgcn_mfma_f32_16x16x32_bf16(         \
                    af[mi], bv[ni], acc[mi][ni], 0, 0, 0);                     \
        _Pragma("unroll")                                                      \
        for (int mi = 0; mi < 4; mi++)                                         \
            _Pragma("unroll")                                                  \
            for (int ni = 0; ni < 4; ni++)                                     \
                acc[4 + mi][ni] = __builtin_amdgcn_mfma_f32_16x16x32_bf16(     \
                    af2[mi], bv[ni], acc[4 + mi][ni], 0, 0, 0);                \
        __builtin_amdgcn_s_setprio(0);                                         \
    }

    #pragma unroll 1
    for (int nt = 0; nt < 8; ++nt) {
        // hoist epilogue operands; over-drained harmlessly at first boundary
        float bb[4], ww[4];
        #pragma unroll
        for (int ni = 0; ni < 4; ni++) {
            const int n = nt * 256 + wc * 64 + ni * 16 + c;
            bb[ni] = b1e[n];
            ww[ni] = w2e[n];
        }
        #pragma unroll 1
        for (int kt4 = 0; kt4 < 32; kt4 += 4) {
            KT_ITER(0)
            KT_ITER(1)
            KT_ITER(2)
            KT_ITER(3)
        }
        // epilogue: +b1, ReLU, *W2, reduce across the 16 c-lanes, LDS-accumulate
        #pragma unroll
        for (int mi = 0; mi < 8; mi++)
            #pragma unroll
            for (int r = 0; r < 4; r++) {
                float v = 0.f;
                #pragma unroll
                for (int ni = 0; ni < 4; ni++) {
                    float h = fmaxf(acc[mi][ni][r] + bb[ni], 0.f);
                    v = fmaf(h, ww[ni], v);
                    acc[mi][ni][r] = 0.f;
                }
                v += __shfl_xor(v, 1); v += __shfl_xor(v, 2);
                v += __shfl_xor(v, 4); v += __shfl_xor(v, 8);
                if (c == 0) atomicAdd(&rsum[wr * 128 + mi * 16 + q * 4 + r], v);
            }
    }
#undef KT_ITER

    // drain dead tail stages, then final reduce + sigmoid + mean
    asm volatile("s_waitcnt vmcnt(0)" ::: "memory");
    __syncthreads();
    if (tid < 256) {
        float z = rsum[tid] + b2[e];
        float s = 1.f / (1.f + __expf(-z));
        atomicAdd(&out[mbase + tid], s * (1.0f / NEXP));
    }
}

// ---------- slow-but-correct fallback (only if ws too small) ----------
__global__ __launch_bounds__(256) void fallback_kernel(
        const float* __restrict__ x, const float* __restrict__ W1,
        const float* __restrict__ b1, const float* __restrict__ W2,
        const float* __restrict__ b2, float* __restrict__ out)
{
    __shared__ float xs[64 * 128];   // 32 KB
    __shared__ float zsum[64];
    const int e  = blockIdx.y;
    const int r0 = blockIdx.x * 64;
    const int tid = threadIdx.x;
    if (tid < 64) zsum[tid] = 0.f;
    const float* W1e = W1 + (size_t)e * INSZ * HID;

    for (int hg = 0; hg < 8; hg++) {
        const int h = hg * 256 + tid;
        float acc[64];
        #pragma unroll
        for (int r = 0; r < 64; r++) acc[r] = 0.f;
        for (int ic = 0; ic < 8; ic++) {
            __syncthreads();
            for (int t = tid; t < 64 * 128; t += 256) {
                int r = t >> 7, i = t & 127;
                xs[t] = x[(size_t)(r0 + r) * INSZ + ic * 128 + i];
            }
            __syncthreads();
            for (int i = 0; i < 128; i++) {
                float wv = W1e[(size_t)(ic * 128 + i) * HID + h];
                #pragma unroll
                for (int r = 0; r < 64; r++)
                    acc[r] = fmaf(xs[r * 128 + i], wv, acc[r]);
            }
        }
        const float bb = b1[e * HID + h];
        const float ww = W2[e * HID + h];
        #pragma unroll
        for (int r = 0; r < 64; r++) {
            float v = fmaxf(acc[r] + bb, 0.f) * ww;
            v += __shfl_xor(v, 1);  v += __shfl_xor(v, 2);  v += __shfl_xor(v, 4);
            v += __shfl_xor(v, 8);  v += __shfl_xor(v, 16); v += __shfl_xor(v, 32);
            if ((tid & 63) == 0) atomicAdd(&zsum[r], v);
        }
    }
    __syncthreads();
    if (tid < 64) {
        float z = zsum[tid] + b2[e];
        atomicAdd(&out[r0 + tid], (1.f / (1.f + __expf(-z))) * (1.0f / NEXP));
    }
}

extern "C" void kernel_launch(void* const* d_in, const int* in_sizes, int n_in,
                              void* d_out, int out_size, void* d_ws, size_t ws_size,
                              hipStream_t stream) {
    const float* x  = (const float*)d_in[0];
    const float* W1 = (const float*)d_in[1];
    const float* b1 = (const float*)d_in[2];
    const float* W2 = (const float*)d_in[3];
    const float* b2 = (const float*)d_in[4];
    float* out = (float*)d_out;

    hipMemsetAsync(out, 0, (size_t)out_size * sizeof(float), stream);

    const size_t xb_bytes = (size_t)NB * INSZ * sizeof(u16);          // 16 MB
    const size_t wt_bytes = (size_t)NEXP * HID * INSZ * sizeof(u16);  // 126 MB
    if (ws_size >= xb_bytes + wt_bytes) {
        u16* Xb = (u16*)d_ws;
        u16* Wt = (u16*)((char*)d_ws + xb_bytes);
        conv_x<<<dim3((NB * INSZ) / 2048), 256, 0, stream>>>(x, Xb);
        conv_w1<<<dim3(INSZ / 32, HID / 256, NEXP), 256, 0, stream>>>(W1, Wt);
        fused_mlp<<<dim3(NB / 256, NEXP), 512, 0, stream>>>(Xb, Wt, b1, W2, b2, out);
    } else {
        fallback_kernel<<<dim3(NB / 64, NEXP), 256, 0, stream>>>(x, W1, b1, W2, b2, out);
    }
}